// Round 7
// baseline (268.602 us; speedup 1.0000x reference)
//
#include <hip/hip_runtime.h>
#include <hip/hip_bf16.h>

typedef unsigned short u16;
typedef short bf16x8 __attribute__((ext_vector_type(8)));
typedef float f32x4 __attribute__((ext_vector_type(4)));
typedef float f32x16 __attribute__((ext_vector_type(16)));
typedef unsigned short u16x4 __attribute__((ext_vector_type(4)));
typedef unsigned u32x4 __attribute__((ext_vector_type(4)));

// scores pre-scaled by log2(e)/8 (folded into Wq, bq) so softmax is pure exp2
#define SCALE_Q 0.18033688011112042f

__device__ __forceinline__ u16 f2b(float f) {
    __hip_bfloat16 h = __float2bfloat16(f);   // hw v_cvt (RNE) on gfx950
    return *reinterpret_cast<u16*>(&h);
}

__device__ __forceinline__ unsigned cvt_pk_bf16(float lo, float hi) {
    unsigned r;
    asm("v_cvt_pk_bf16_f32 %0, %1, %2" : "=v"(r) : "v"(lo), "v"(hi));
    return r;
}

__device__ __forceinline__ void load_lds16(const void* g, void* l) {
    __builtin_amdgcn_global_load_lds(
        (const __attribute__((address_space(1))) void*)g,
        (__attribute__((address_space(3))) void*)l, 16, 0, 0);
}

// ---------------- prep: hidden * channel_importance -> bf16 ----------------
__global__ __launch_bounds__(256) void prep_hidden(
    const float* __restrict__ x, const float* __restrict__ ci, u16* __restrict__ hbuf) {
    size_t i = ((size_t)blockIdx.x * 256 + threadIdx.x) * 4;
    float4 v = *(const float4*)(x + i);
    int c = (int)(i % 768);
    u16x4 o;
    o.x = f2b(v.x * ci[c]);     o.y = f2b(v.y * ci[c + 1]);
    o.z = f2b(v.z * ci[c + 2]); o.w = f2b(v.w * ci[c + 3]);
    *(u16x4*)(hbuf + i) = o;
}

// ---------------- prep: transpose weights to [N][K] bf16 ----------------
__global__ __launch_bounds__(256) void transpose_w(
    const float* __restrict__ Wq, const float* __restrict__ Wk,
    const float* __restrict__ Wv, const float* __restrict__ Wo,
    const float* __restrict__ cc, u16* __restrict__ wqkvt, u16* __restrict__ wot) {
    __shared__ float tile[32][33];
    int z = blockIdx.z;
    const float* src = (z == 0) ? Wq : (z == 1) ? Wk : (z == 2) ? Wv : Wo;
    u16* dst = (z < 3) ? (wqkvt + (size_t)z * 768 * 768) : wot;
    int tx = threadIdx.x & 31, ty = threadIdx.x >> 5;
    int k0 = blockIdx.x * 32, n0 = blockIdx.y * 32;
    #pragma unroll
    for (int i = ty; i < 32; i += 8) {
        float v = src[(size_t)(k0 + i) * 768 + n0 + tx];
        if (z == 3) v *= cc[k0 + i];
        if (z == 0) v *= SCALE_Q;
        tile[i][tx] = v;
    }
    __syncthreads();
    #pragma unroll
    for (int i = ty; i < 32; i += 8)
        dst[(size_t)(n0 + i) * 768 + k0 + tx] = f2b(tile[tx][i]);
}

__global__ __launch_bounds__(256) void bias_cat(
    const float* __restrict__ bq, const float* __restrict__ bk,
    const float* __restrict__ bv, float* __restrict__ biasq) {
    int i = blockIdx.x * 256 + threadIdx.x;
    biasq[i] = (i < 768) ? bq[i] * SCALE_Q : (i < 1536) ? bk[i - 768] : bv[i - 1536];
}

// ---------------- GEMM: C[M][N] = A[M][K] @ Bt[N][K]^T + bias ----------------
template <int F32OUT>
__global__ __launch_bounds__(256) void gemm_bt(
    const u16* __restrict__ A, const u16* __restrict__ Bt,
    const float* __restrict__ bias, void* __restrict__ Cout,
    int M, int N, int K, int NTN) {
    __shared__ u16 lA[128 * 64];
    __shared__ u16 lB[128 * 64];
    int nwg = gridDim.x;
    int bid = blockIdx.x;
    int wg = ((nwg & 7) == 0) ? ((bid & 7) * (nwg >> 3) + (bid >> 3)) : bid;
    int mt = wg / NTN, nt = wg % NTN;
    int row0 = mt << 7, col0 = nt << 7;
    int tid = threadIdx.x;
    int lane = tid & 63, wv = tid >> 6;
    int wm = (wv >> 1) * 64, wn = (wv & 1) * 64;
    int l15 = lane & 15, hi = lane >> 4;

    f32x4 acc[4][4] = {};

    for (int kt = 0; kt < K; kt += 64) {
        __syncthreads();
        #pragma unroll
        for (int p = 0; p < 4; ++p) {
            int cl = p * 256 + tid;
            int rr = cl >> 3;
            int cc = (cl & 7) ^ (rr & 7);
            int lo = (p * 256 + (wv << 6)) << 3;
            load_lds16(A + (size_t)(row0 + rr) * K + kt + cc * 8, &lA[lo]);
            load_lds16(Bt + (size_t)(col0 + rr) * K + kt + cc * 8, &lB[lo]);
        }
        __syncthreads();
        __builtin_amdgcn_s_setprio(1);
        #pragma unroll
        for (int ks = 0; ks < 2; ++ks) {
            bf16x8 af[4], bf[4];
            #pragma unroll
            for (int i = 0; i < 4; ++i) {
                int ra = wm + i * 16 + l15;
                af[i] = *(const bf16x8*)&lA[ra * 64 + (((ks << 2) + hi) ^ (ra & 7)) * 8];
                int rb = wn + i * 16 + l15;
                bf[i] = *(const bf16x8*)&lB[rb * 64 + (((ks << 2) + hi) ^ (rb & 7)) * 8];
            }
            #pragma unroll
            for (int mi = 0; mi < 4; ++mi)
                #pragma unroll
                for (int ni = 0; ni < 4; ++ni)
                    acc[mi][ni] = __builtin_amdgcn_mfma_f32_16x16x32_bf16(
                        af[mi], bf[ni], acc[mi][ni], 0, 0, 0);
        }
        __builtin_amdgcn_s_setprio(0);
    }

    #pragma unroll
    for (int mi = 0; mi < 4; ++mi) {
        int rbase = row0 + wm + mi * 16 + hi * 4;
        #pragma unroll
        for (int ni = 0; ni < 4; ++ni) {
            int c = col0 + wn + ni * 16 + l15;
            float bv = bias[c];
            #pragma unroll
            for (int j = 0; j < 4; ++j) {
                float o = acc[mi][ni][j] + bv;
                if (F32OUT) ((float*)Cout)[(size_t)(rbase + j) * N + c] = o;
                else        ((u16*)Cout)[(size_t)(rbase + j) * N + c] = f2b(o);
            }
        }
    }
}

// ---------------- flash attention (swapped QK^T, in-register P, permlane) ----
// 32x32x16 MFMAs, S^T = mfma(K,Q). No-max softmax (exp2-domain, bounded).
// P->PV fragments via v_permlane32_swap_b32 (2 per m-step). V pack via v_perm.
// t-loop unrolled x2 so LDS buffer pointers are compile-time (addresses hoisted).
__global__ __launch_bounds__(256) void attn_kernel(
    const u16* __restrict__ QKV, u16* __restrict__ ctx) {
    __shared__ u16 lK[2][64 * 64];    // K-tile [kv][d], XOR-swizzled 16B chunks
    __shared__ u16 lV[2][64 * 68];    // V^T tile [d][kv], +4 pad

    int bid = blockIdx.x;
    int wg = (bid & 7) * 192 + (bid >> 3);   // XCD swizzle
    int bh = wg >> 3, qt = wg & 7;
    int b = bh / 12, h = bh % 12;
    int tid = threadIdx.x;
    int lane = tid & 63, wv = tid >> 6;
    int l31 = lane & 31;
    int hb = lane >> 5;                      // 0/1 half of wave

    const u16* Qb = QKV + (size_t)b * 1024 * 2304 + h * 64;
    const u16* Kb = Qb + 768;
    const u16* Vb = Qb + 1536;

    int qrow0 = qt * 128 + wv * 32;

    // Q as B-operand: lane -> col q = l31, k(d) slots
    bf16x8 qf[4];
    #pragma unroll
    for (int ks = 0; ks < 4; ++ks)
        qf[ks] = *(const bf16x8*)(Qb + (size_t)(qrow0 + l31) * 2304 + ks * 16 + hb * 8);

    bf16x8 ones;
    #pragma unroll
    for (int i = 0; i < 8; ++i) ones[i] = (short)0x3F80;  // bf16 1.0

    f32x16 accO0 = {}, accO1 = {};   // d-blocks 0/1
    f32x16 accL = {};                // row sums, same C-layout rows as accO

    // staging geometry
    int jj0 = (tid & 31) * 2;                   // V: 2 adjacent kv rows / thread
    int d0v = (tid >> 5) << 3;                  // V: 8-wide d block

    u16* lK0 = &lK[0][0]; u16* lK1 = &lK[1][0];
    u16* lV0 = &lV[0][0]; u16* lV1 = &lV[1][0];

    // ---- prologue: stage tile 0 into buffer 0 ----
    #pragma unroll
    for (int p = 0; p < 2; ++p) {
        int rr = (p * 256 + tid) >> 3;
        int cc = ((p * 256 + tid) & 7) ^ (rr & 7);
        load_lds16(Kb + (size_t)rr * 2304 + cc * 8, &lK0[(p * 256 + (wv << 6)) << 3]);
    }
    {
        bf16x8 g0 = *(const bf16x8*)(Vb + (size_t)jj0 * 2304 + d0v);
        bf16x8 g1 = *(const bf16x8*)(Vb + (size_t)(jj0 + 1) * 2304 + d0v);
        const unsigned* a0 = (const unsigned*)&g0;
        const unsigned* a1 = (const unsigned*)&g1;
        #pragma unroll
        for (int w = 0; w < 4; ++w) {
            *(unsigned*)&lV0[(d0v + 2 * w) * 68 + jj0] =
                __builtin_amdgcn_perm(a1[w], a0[w], 0x05040100);
            *(unsigned*)&lV0[(d0v + 2 * w + 1) * 68 + jj0] =
                __builtin_amdgcn_perm(a1[w], a0[w], 0x07060302);
        }
    }
    __syncthreads();

#define TILE_BODY(T, LKC, LKN, LVC, LVN)                                        \
    {                                                                           \
        bf16x8 nv0, nv1;                                                        \
        const bool pref = (T) < 15;                                             \
        if (pref) {                                                             \
            size_t kt1 = (size_t)((T) + 1) * 64;                                \
            _Pragma("unroll")                                                   \
            for (int p = 0; p < 2; ++p) {                                       \
                int rr = (p * 256 + tid) >> 3;                                  \
                int cc = ((p * 256 + tid) & 7) ^ (rr & 7);                      \
                load_lds16(Kb + (kt1 + rr) * 2304 + cc * 8,                     \
                           &(LKN)[(p * 256 + (wv << 6)) << 3]);                 \
            }                                                                   \
            nv0 = *(const bf16x8*)(Vb + (kt1 + jj0) * 2304 + d0v);              \
            nv1 = *(const bf16x8*)(Vb + (kt1 + jj0 + 1) * 2304 + d0v);          \
        }                                                                       \
        f32x16 accs0 = {}, accs1 = {};                                          \
        __builtin_amdgcn_s_setprio(1);                                          \
        _Pragma("unroll")                                                       \
        for (int ks = 0; ks < 4; ++ks) {                                        \
            int ch = ((2 * ks + hb) ^ (l31 & 7)) * 8;                           \
            bf16x8 kf0 = *(const bf16x8*)&(LKC)[l31 * 64 + ch];                 \
            bf16x8 kf1 = *(const bf16x8*)&(LKC)[(32 + l31) * 64 + ch];          \
            accs0 = __builtin_amdgcn_mfma_f32_32x32x16_bf16(kf0, qf[ks], accs0, 0, 0, 0); \
            accs1 = __builtin_amdgcn_mfma_f32_32x32x16_bf16(kf1, qf[ks], accs1, 0, 0, 0); \
        }                                                                       \
        __builtin_amdgcn_s_setprio(0);                                          \
        unsigned W0[8], W1[8];                                                  \
        _Pragma("unroll")                                                       \
        for (int w = 0; w < 8; ++w) {                                           \
            W0[w] = cvt_pk_bf16(exp2f(accs0[2 * w]), exp2f(accs0[2 * w + 1]));  \
            W1[w] = cvt_pk_bf16(exp2f(accs1[2 * w]), exp2f(accs1[2 * w + 1]));  \
        }                                                                       \
        __builtin_amdgcn_s_setprio(1);                                          \
        _Pragma("unroll")                                                       \
        for (int m = 0; m < 4; ++m) {                                           \
            int a = 4 * (m & 1);                                                \
            unsigned pwx, pwy, pwz, pww;                                        \
            if (m < 2) { pwx = W0[a]; pwy = W0[a+1]; pwz = W0[a+2]; pww = W0[a+3]; } \
            else       { pwx = W1[a]; pwy = W1[a+1]; pwz = W1[a+2]; pww = W1[a+3]; } \
            asm volatile("v_permlane32_swap_b32 %0, %1" : "+v"(pwx), "+v"(pwz)); \
            asm volatile("v_permlane32_swap_b32 %0, %1" : "+v"(pwy), "+v"(pww)); \
            u32x4 pw; pw.x = pwx; pw.y = pwy; pw.z = pwz; pw.w = pww;           \
            bf16x8 pa = *(bf16x8*)&pw;                                          \
            accL = __builtin_amdgcn_mfma_f32_32x32x16_bf16(pa, ones, accL, 0, 0, 0); \
            bf16x8 vf0 = *(const bf16x8*)&(LVC)[l31 * 68 + m * 16 + hb * 8];    \
            bf16x8 vf1 = *(const bf16x8*)&(LVC)[(32 + l31) * 68 + m * 16 + hb * 8]; \
            accO0 = __builtin_amdgcn_mfma_f32_32x32x16_bf16(pa, vf0, accO0, 0, 0, 0); \
            accO1 = __builtin_amdgcn_mfma_f32_32x32x16_bf16(pa, vf1, accO1, 0, 0, 0); \
        }                                                                       \
        __builtin_amdgcn_s_setprio(0);                                          \
        if (pref) {                                                             \
            const unsigned* a0 = (const unsigned*)&nv0;                         \
            const unsigned* a1 = (const unsigned*)&nv1;                         \
            _Pragma("unroll")                                                   \
            for (int w = 0; w < 4; ++w) {                                       \
                *(unsigned*)&(LVN)[(d0v + 2 * w) * 68 + jj0] =                  \
                    __builtin_amdgcn_perm(a1[w], a0[w], 0x05040100);            \
                *(unsigned*)&(LVN)[(d0v + 2 * w + 1) * 68 + jj0] =              \
                    __builtin_amdgcn_perm(a1[w], a0[w], 0x07060302);            \
            }                                                                   \
        }                                                                       \
        __syncthreads();                                                        \
    }

    for (int tt = 0; tt < 16; tt += 2) {
        TILE_BODY(tt,     lK0, lK1, lV0, lV1);
        TILE_BODY(tt + 1, lK1, lK0, lV1, lV0);
    }
#undef TILE_BODY

    // ---- epilogue: O /= L (row layouts match), write ctx bf16 [B*S][768] ----
    #pragma unroll
    for (int r = 0; r < 16; ++r) {
        float inv = 1.0f / accL[r];
        int q = (r & 3) + 8 * (r >> 2) + hb * 4;
        size_t row = (size_t)(b * 1024 + qrow0 + q);
        ctx[row * 768 + h * 64 + l31]      = f2b(accO0[r] * inv);
        ctx[row * 768 + h * 64 + 32 + l31] = f2b(accO1[r] * inv);
    }
}

// ---------------- launcher ----------------
extern "C" void kernel_launch(void* const* d_in, const int* in_sizes, int n_in,
                              void* d_out, int out_size, void* d_ws, size_t ws_size,
                              hipStream_t stream) {
    const float* x  = (const float*)d_in[0];
    const float* ci = (const float*)d_in[1];
    const float* cc = (const float*)d_in[2];
    const float* Wq = (const float*)d_in[3];
    const float* bq = (const float*)d_in[4];
    const float* Wk = (const float*)d_in[5];
    const float* bk = (const float*)d_in[6];
    const float* Wv = (const float*)d_in[7];
    const float* bv = (const float*)d_in[8];
    const float* Wo = (const float*)d_in[9];
    const float* bo = (const float*)d_in[10];
    float* out = (float*)d_out;

    unsigned char* ws = (unsigned char*)d_ws;
    size_t off = 0;
    auto alloc = [&](size_t bytes) {
        void* p = ws + off;
        off += (bytes + 255) & ~(size_t)255;
        return p;
    };
    u16*   hbuf  = (u16*)  alloc((size_t)16384 * 768 * 2);
    u16*   wqkvt = (u16*)  alloc((size_t)2304 * 768 * 2);
    u16*   wot   = (u16*)  alloc((size_t)768 * 768 * 2);
    float* biasq = (float*)alloc(2304 * 4);
    u16*   qkv   = (u16*)  alloc((size_t)16384 * 2304 * 2);
    u16*   ctx   = (u16*)  alloc((size_t)16384 * 768 * 2);

    prep_hidden<<<12288, 256, 0, stream>>>(x, ci, hbuf);
    transpose_w<<<dim3(24, 24, 4), 256, 0, stream>>>(Wq, Wk, Wv, Wo, cc, wqkvt, wot);
    bias_cat<<<9, 256, 0, stream>>>(bq, bk, bv, biasq);
    gemm_bt<0><<<2304, 256, 0, stream>>>(hbuf, wqkvt, biasq, qkv, 16384, 2304, 768, 18);
    attn_kernel<<<1536, 256, 0, stream>>>(qkv, ctx);
    gemm_bt<1><<<768, 256, 0, stream>>>(ctx, wot, bo, out, 16384, 768, 768, 6);
}

// Round 8
// 224.798 us; speedup vs baseline: 1.1949x; 1.1949x over previous
//
#include <hip/hip_runtime.h>
#include <hip/hip_bf16.h>

typedef unsigned short u16;
typedef short bf16x8 __attribute__((ext_vector_type(8)));
typedef float f32x4 __attribute__((ext_vector_type(4)));
typedef float f32x16 __attribute__((ext_vector_type(16)));
typedef unsigned short u16x4 __attribute__((ext_vector_type(4)));
typedef unsigned u32x4 __attribute__((ext_vector_type(4)));

// scores pre-scaled by log2(e)/8 (folded into Wq, bq) so softmax is pure exp2
#define SCALE_Q 0.18033688011112042f

__device__ __forceinline__ u16 f2b(float f) {
    __hip_bfloat16 h = __float2bfloat16(f);   // hw v_cvt (RNE) on gfx950
    return *reinterpret_cast<u16*>(&h);
}

__device__ __forceinline__ unsigned cvt_pk_bf16(float lo, float hi) {
    unsigned r;
    asm("v_cvt_pk_bf16_f32 %0, %1, %2" : "=v"(r) : "v"(lo), "v"(hi));
    return r;
}

__device__ __forceinline__ void load_lds16(const void* g, void* l) {
    __builtin_amdgcn_global_load_lds(
        (const __attribute__((address_space(1))) void*)g,
        (__attribute__((address_space(3))) void*)l, 16, 0, 0);
}

// ---------------- prep: hidden * channel_importance -> bf16 ----------------
__global__ __launch_bounds__(256) void prep_hidden(
    const float* __restrict__ x, const float* __restrict__ ci, u16* __restrict__ hbuf) {
    size_t i = ((size_t)blockIdx.x * 256 + threadIdx.x) * 4;
    float4 v = *(const float4*)(x + i);
    int c = (int)(i % 768);
    u16x4 o;
    o.x = f2b(v.x * ci[c]);     o.y = f2b(v.y * ci[c + 1]);
    o.z = f2b(v.z * ci[c + 2]); o.w = f2b(v.w * ci[c + 3]);
    *(u16x4*)(hbuf + i) = o;
}

// ---------------- prep: transpose weights to [N][K] bf16 ----------------
__global__ __launch_bounds__(256) void transpose_w(
    const float* __restrict__ Wq, const float* __restrict__ Wk,
    const float* __restrict__ Wv, const float* __restrict__ Wo,
    const float* __restrict__ cc, u16* __restrict__ wqkvt, u16* __restrict__ wot) {
    __shared__ float tile[32][33];
    int z = blockIdx.z;
    const float* src = (z == 0) ? Wq : (z == 1) ? Wk : (z == 2) ? Wv : Wo;
    u16* dst = (z < 3) ? (wqkvt + (size_t)z * 768 * 768) : wot;
    int tx = threadIdx.x & 31, ty = threadIdx.x >> 5;
    int k0 = blockIdx.x * 32, n0 = blockIdx.y * 32;
    #pragma unroll
    for (int i = ty; i < 32; i += 8) {
        float v = src[(size_t)(k0 + i) * 768 + n0 + tx];
        if (z == 3) v *= cc[k0 + i];
        if (z == 0) v *= SCALE_Q;
        tile[i][tx] = v;
    }
    __syncthreads();
    #pragma unroll
    for (int i = ty; i < 32; i += 8)
        dst[(size_t)(n0 + i) * 768 + k0 + tx] = f2b(tile[tx][i]);
}

__global__ __launch_bounds__(256) void bias_cat(
    const float* __restrict__ bq, const float* __restrict__ bk,
    const float* __restrict__ bv, float* __restrict__ biasq) {
    int i = blockIdx.x * 256 + threadIdx.x;
    biasq[i] = (i < 768) ? bq[i] * SCALE_Q : (i < 1536) ? bk[i - 768] : bv[i - 1536];
}

// ---------------- GEMM: C[M][N] = A[M][K] @ Bt[N][K]^T + bias ----------------
template <int F32OUT>
__global__ __launch_bounds__(256) void gemm_bt(
    const u16* __restrict__ A, const u16* __restrict__ Bt,
    const float* __restrict__ bias, void* __restrict__ Cout,
    int M, int N, int K, int NTN) {
    __shared__ u16 lA[128 * 64];
    __shared__ u16 lB[128 * 64];
    int nwg = gridDim.x;
    int bid = blockIdx.x;
    int wg = ((nwg & 7) == 0) ? ((bid & 7) * (nwg >> 3) + (bid >> 3)) : bid;
    int mt = wg / NTN, nt = wg % NTN;
    int row0 = mt << 7, col0 = nt << 7;
    int tid = threadIdx.x;
    int lane = tid & 63, wv = tid >> 6;
    int wm = (wv >> 1) * 64, wn = (wv & 1) * 64;
    int l15 = lane & 15, hi = lane >> 4;

    f32x4 acc[4][4] = {};

    for (int kt = 0; kt < K; kt += 64) {
        __syncthreads();
        #pragma unroll
        for (int p = 0; p < 4; ++p) {
            int cl = p * 256 + tid;
            int rr = cl >> 3;
            int cc = (cl & 7) ^ (rr & 7);
            int lo = (p * 256 + (wv << 6)) << 3;
            load_lds16(A + (size_t)(row0 + rr) * K + kt + cc * 8, &lA[lo]);
            load_lds16(Bt + (size_t)(col0 + rr) * K + kt + cc * 8, &lB[lo]);
        }
        __syncthreads();
        __builtin_amdgcn_s_setprio(1);
        #pragma unroll
        for (int ks = 0; ks < 2; ++ks) {
            bf16x8 af[4], bf[4];
            #pragma unroll
            for (int i = 0; i < 4; ++i) {
                int ra = wm + i * 16 + l15;
                af[i] = *(const bf16x8*)&lA[ra * 64 + (((ks << 2) + hi) ^ (ra & 7)) * 8];
                int rb = wn + i * 16 + l15;
                bf[i] = *(const bf16x8*)&lB[rb * 64 + (((ks << 2) + hi) ^ (rb & 7)) * 8];
            }
            #pragma unroll
            for (int mi = 0; mi < 4; ++mi)
                #pragma unroll
                for (int ni = 0; ni < 4; ++ni)
                    acc[mi][ni] = __builtin_amdgcn_mfma_f32_16x16x32_bf16(
                        af[mi], bf[ni], acc[mi][ni], 0, 0, 0);
        }
        __builtin_amdgcn_s_setprio(0);
    }

    #pragma unroll
    for (int mi = 0; mi < 4; ++mi) {
        int rbase = row0 + wm + mi * 16 + hi * 4;
        #pragma unroll
        for (int ni = 0; ni < 4; ++ni) {
            int c = col0 + wn + ni * 16 + l15;
            float bv = bias[c];
            #pragma unroll
            for (int j = 0; j < 4; ++j) {
                float o = acc[mi][ni][j] + bv;
                if (F32OUT) ((float*)Cout)[(size_t)(rbase + j) * N + c] = o;
                else        ((u16*)Cout)[(size_t)(rbase + j) * N + c] = f2b(o);
            }
        }
    }
}

// ---------------- flash attention (swapped QK^T, zero-shuffle PV) ----------
// 32x32x16 MFMAs, S^T = mfma(K,Q): lane's 32 S-values all belong to q = lane&31.
// No-max softmax (exp2-domain, bounded). PV needs NO cross-lane exchange:
// MFMA k-slots are permutation-invariant when BOTH operands use the same map.
// Lane(hb,q)'s accs regs 0..7 hold kv rows (j&3)+8*(j>>2)+4*hb, so storing V^T
// columns at bit-swapped index (b2<->b3) makes the contiguous V-read supply
// exactly those kv's: pa = cvt_pk words in natural register order.
__global__ __launch_bounds__(256) void attn_kernel(
    const u16* __restrict__ QKV, u16* __restrict__ ctx) {
    __shared__ u16 lK[2][64 * 64];    // K-tile [kv][d], XOR-swizzled 16B chunks
    __shared__ u16 lV[2][64 * 68];    // V^T tile [d][kv'], kv' = b2<->b3 swap, +4 pad

    int bid = blockIdx.x;
    int wg = (bid & 7) * 192 + (bid >> 3);   // XCD swizzle
    int bh = wg >> 3, qt = wg & 7;
    int b = bh / 12, h = bh % 12;
    int tid = threadIdx.x;
    int lane = tid & 63, wv = tid >> 6;
    int l31 = lane & 31;
    int hb = lane >> 5;

    const u16* Qb = QKV + (size_t)b * 1024 * 2304 + h * 64;
    const u16* Kb = Qb + 768;
    const u16* Vb = Qb + 1536;

    int qrow0 = qt * 128 + wv * 32;

    // Q as B-operand: lane -> col q = l31, k(d) slots
    bf16x8 qf[4];
    #pragma unroll
    for (int ks = 0; ks < 4; ++ks)
        qf[ks] = *(const bf16x8*)(Qb + (size_t)(qrow0 + l31) * 2304 + ks * 16 + hb * 8);

    bf16x8 ones;
    #pragma unroll
    for (int i = 0; i < 8; ++i) ones[i] = (short)0x3F80;  // bf16 1.0

    f32x16 accO[2] = {};   // [d-block 0/1]
    f32x16 accL = {};      // row sums, same C-layout rows as accO

    // staging geometry
    int jj0 = (tid & 31) * 2;                   // V: 2 adjacent kv rows / thread
    int jjs = (jj0 & ~12) | ((jj0 & 4) << 1) | ((jj0 & 8) >> 1);  // b2<->b3 swap
    int d0v = (tid >> 5) << 3;                  // V: 8-wide d block

    // ---- prologue: stage tile 0 into buffer 0 ----
    #pragma unroll
    for (int p = 0; p < 2; ++p) {
        int rr = (p * 256 + tid) >> 3;
        int cc = ((p * 256 + tid) & 7) ^ (rr & 7);
        load_lds16(Kb + (size_t)rr * 2304 + cc * 8, &lK[0][(p * 256 + (wv << 6)) << 3]);
    }
    {
        bf16x8 g0 = *(const bf16x8*)(Vb + (size_t)jj0 * 2304 + d0v);
        bf16x8 g1 = *(const bf16x8*)(Vb + (size_t)(jj0 + 1) * 2304 + d0v);
        const unsigned* a0 = (const unsigned*)&g0;
        const unsigned* a1 = (const unsigned*)&g1;
        #pragma unroll
        for (int w = 0; w < 4; ++w) {
            *(unsigned*)&lV[0][(d0v + 2 * w) * 68 + jjs] =
                __builtin_amdgcn_perm(a1[w], a0[w], 0x05040100);
            *(unsigned*)&lV[0][(d0v + 2 * w + 1) * 68 + jjs] =
                __builtin_amdgcn_perm(a1[w], a0[w], 0x07060302);
        }
    }
    __syncthreads();

    int cur = 0;
    for (int t = 0; t < 16; ++t) {
        // ---- issue prefetch for tile t+1 into buffer cur^1 (early) ----
        bf16x8 nv0, nv1;
        if (t < 15) {
            size_t kt1 = (size_t)(t + 1) * 64;
            #pragma unroll
            for (int p = 0; p < 2; ++p) {
                int rr = (p * 256 + tid) >> 3;
                int cc = ((p * 256 + tid) & 7) ^ (rr & 7);
                load_lds16(Kb + (kt1 + rr) * 2304 + cc * 8,
                           &lK[cur ^ 1][(p * 256 + (wv << 6)) << 3]);
            }
            nv0 = *(const bf16x8*)(Vb + (kt1 + jj0) * 2304 + d0v);
            nv1 = *(const bf16x8*)(Vb + (kt1 + jj0 + 1) * 2304 + d0v);
        }

        // ---- S^T = mfma(K, Q): accs[kvb] C-layout: col=q=l31, row=kv_local ----
        f32x16 accs[2] = {};
        __builtin_amdgcn_s_setprio(1);
        #pragma unroll
        for (int kvb = 0; kvb < 2; ++kvb)
            #pragma unroll
            for (int ks = 0; ks < 4; ++ks) {
                bf16x8 kf = *(const bf16x8*)&lK[cur][
                    (kvb * 32 + l31) * 64 + (((ks << 1) + hb) ^ (l31 & 7)) * 8];
                accs[kvb] = __builtin_amdgcn_mfma_f32_32x32x16_bf16(
                    kf, qf[ks], accs[kvb], 0, 0, 0);
            }
        __builtin_amdgcn_s_setprio(0);

        // ---- P = exp2(S) packed to bf16 pairs (no-max: scores bounded) ----
        unsigned W[2][8];
        #pragma unroll
        for (int kvb = 0; kvb < 2; ++kvb)
            #pragma unroll
            for (int w = 0; w < 8; ++w)
                W[kvb][w] = cvt_pk_bf16(exp2f(accs[kvb][2 * w]), exp2f(accs[kvb][2 * w + 1]));

        // ---- PV: pa = W words directly (k-permuted V layout), accumulate O, L ----
        __builtin_amdgcn_s_setprio(1);
        #pragma unroll
        for (int m = 0; m < 4; ++m) {
            int kvb = m >> 1;
            int a = 4 * (m & 1);
            u32x4 pw;
            pw.x = W[kvb][a];     pw.y = W[kvb][a + 1];
            pw.z = W[kvb][a + 2]; pw.w = W[kvb][a + 3];
            bf16x8 pa = *(bf16x8*)&pw;
            accL = __builtin_amdgcn_mfma_f32_32x32x16_bf16(pa, ones, accL, 0, 0, 0);
            #pragma unroll
            for (int db = 0; db < 2; ++db) {
                bf16x8 vf = *(const bf16x8*)&lV[cur][
                    (db * 32 + l31) * 68 + m * 16 + hb * 8];
                accO[db] = __builtin_amdgcn_mfma_f32_32x32x16_bf16(pa, vf, accO[db], 0, 0, 0);
            }
        }
        __builtin_amdgcn_s_setprio(0);

        // ---- write-late: V(t+1) pack into lV[cur^1] at permuted columns ----
        if (t < 15) {
            const unsigned* a0 = (const unsigned*)&nv0;
            const unsigned* a1 = (const unsigned*)&nv1;
            #pragma unroll
            for (int w = 0; w < 4; ++w) {
                *(unsigned*)&lV[cur ^ 1][(d0v + 2 * w) * 68 + jjs] =
                    __builtin_amdgcn_perm(a1[w], a0[w], 0x05040100);
                *(unsigned*)&lV[cur ^ 1][(d0v + 2 * w + 1) * 68 + jjs] =
                    __builtin_amdgcn_perm(a1[w], a0[w], 0x07060302);
            }
        }

        __syncthreads();
        cur ^= 1;
    }

    // ---- epilogue: O /= L (row layouts match), write ctx bf16 [B*S][768] ----
    #pragma unroll
    for (int r = 0; r < 16; ++r) {
        float inv = 1.0f / accL[r];
        int q = (r & 3) + 8 * (r >> 2) + hb * 4;
        size_t row = (size_t)(b * 1024 + qrow0 + q);
        ctx[row * 768 + h * 64 + l31]      = f2b(accO[0][r] * inv);
        ctx[row * 768 + h * 64 + 32 + l31] = f2b(accO[1][r] * inv);
    }
}

// ---------------- launcher ----------------
extern "C" void kernel_launch(void* const* d_in, const int* in_sizes, int n_in,
                              void* d_out, int out_size, void* d_ws, size_t ws_size,
                              hipStream_t stream) {
    const float* x  = (const float*)d_in[0];
    const float* ci = (const float*)d_in[1];
    const float* cc = (const float*)d_in[2];
    const float* Wq = (const float*)d_in[3];
    const float* bq = (const float*)d_in[4];
    const float* Wk = (const float*)d_in[5];
    const float* bk = (const float*)d_in[6];
    const float* Wv = (const float*)d_in[7];
    const float* bv = (const float*)d_in[8];
    const float* Wo = (const float*)d_in[9];
    const float* bo = (const float*)d_in[10];
    float* out = (float*)d_out;

    unsigned char* ws = (unsigned char*)d_ws;
    size_t off = 0;
    auto alloc = [&](size_t bytes) {
        void* p = ws + off;
        off += (bytes + 255) & ~(size_t)255;
        return p;
    };
    u16*   hbuf  = (u16*)  alloc((size_t)16384 * 768 * 2);
    u16*   wqkvt = (u16*)  alloc((size_t)2304 * 768 * 2);
    u16*   wot   = (u16*)  alloc((size_t)768 * 768 * 2);
    float* biasq = (float*)alloc(2304 * 4);
    u16*   qkv   = (u16*)  alloc((size_t)16384 * 2304 * 2);
    u16*   ctx   = (u16*)  alloc((size_t)16384 * 768 * 2);

    prep_hidden<<<12288, 256, 0, stream>>>(x, ci, hbuf);
    transpose_w<<<dim3(24, 24, 4), 256, 0, stream>>>(Wq, Wk, Wv, Wo, cc, wqkvt, wot);
    bias_cat<<<9, 256, 0, stream>>>(bq, bk, bv, biasq);
    gemm_bt<0><<<2304, 256, 0, stream>>>(hbuf, wqkvt, biasq, qkv, 16384, 2304, 768, 18);
    attn_kernel<<<1536, 256, 0, stream>>>(qkv, ctx);
    gemm_bt<1><<<768, 256, 0, stream>>>(ctx, wot, bo, out, 16384, 768, 768, 6);
}

// Round 9
// 202.373 us; speedup vs baseline: 1.3273x; 1.1108x over previous
//
#include <hip/hip_runtime.h>
#include <hip/hip_bf16.h>

typedef unsigned short u16;
typedef short bf16x8 __attribute__((ext_vector_type(8)));
typedef float f32x4 __attribute__((ext_vector_type(4)));
typedef float f32x16 __attribute__((ext_vector_type(16)));
typedef unsigned short u16x4 __attribute__((ext_vector_type(4)));
typedef unsigned u32x4 __attribute__((ext_vector_type(4)));

// scores pre-scaled by log2(e)/8 (folded into Wq, bq) so softmax is pure exp2
#define SCALE_Q 0.18033688011112042f

__device__ __forceinline__ u16 f2b(float f) {
    __hip_bfloat16 h = __float2bfloat16(f);   // hw v_cvt (RNE) on gfx950
    return *reinterpret_cast<u16*>(&h);
}

__device__ __forceinline__ unsigned cvt_pk_bf16(float lo, float hi) {
    unsigned r;
    asm("v_cvt_pk_bf16_f32 %0, %1, %2" : "=v"(r) : "v"(lo), "v"(hi));
    return r;
}

__device__ __forceinline__ void load_lds16(const void* g, void* l) {
    __builtin_amdgcn_global_load_lds(
        (const __attribute__((address_space(1))) void*)g,
        (__attribute__((address_space(3))) void*)l, 16, 0, 0);
}

// ---------------- prep: hidden * channel_importance -> bf16 ----------------
__global__ __launch_bounds__(256) void prep_hidden(
    const float* __restrict__ x, const float* __restrict__ ci, u16* __restrict__ hbuf) {
    size_t i = ((size_t)blockIdx.x * 256 + threadIdx.x) * 4;
    float4 v = *(const float4*)(x + i);
    int c = (int)(i % 768);
    u16x4 o;
    o.x = f2b(v.x * ci[c]);     o.y = f2b(v.y * ci[c + 1]);
    o.z = f2b(v.z * ci[c + 2]); o.w = f2b(v.w * ci[c + 3]);
    *(u16x4*)(hbuf + i) = o;
}

// ---------------- prep: transpose weights to [N][K] bf16 ----------------
__global__ __launch_bounds__(256) void transpose_w(
    const float* __restrict__ Wq, const float* __restrict__ Wk,
    const float* __restrict__ Wv, const float* __restrict__ Wo,
    const float* __restrict__ cc, u16* __restrict__ wqkvt, u16* __restrict__ wot) {
    __shared__ float tile[32][33];
    int z = blockIdx.z;
    const float* src = (z == 0) ? Wq : (z == 1) ? Wk : (z == 2) ? Wv : Wo;
    u16* dst = (z < 3) ? (wqkvt + (size_t)z * 768 * 768) : wot;
    int tx = threadIdx.x & 31, ty = threadIdx.x >> 5;
    int k0 = blockIdx.x * 32, n0 = blockIdx.y * 32;
    #pragma unroll
    for (int i = ty; i < 32; i += 8) {
        float v = src[(size_t)(k0 + i) * 768 + n0 + tx];
        if (z == 3) v *= cc[k0 + i];
        if (z == 0) v *= SCALE_Q;
        tile[i][tx] = v;
    }
    __syncthreads();
    #pragma unroll
    for (int i = ty; i < 32; i += 8)
        dst[(size_t)(n0 + i) * 768 + k0 + tx] = f2b(tile[tx][i]);
}

__global__ __launch_bounds__(256) void bias_cat(
    const float* __restrict__ bq, const float* __restrict__ bk,
    const float* __restrict__ bv, float* __restrict__ biasq) {
    int i = blockIdx.x * 256 + threadIdx.x;
    biasq[i] = (i < 768) ? bq[i] * SCALE_Q : (i < 1536) ? bk[i - 768] : bv[i - 1536];
}

// ---------------- GEMM: C[M][N] = A[M][K] @ Bt[N][K]^T + bias ----------------
template <int F32OUT>
__global__ __launch_bounds__(256) void gemm_bt(
    const u16* __restrict__ A, const u16* __restrict__ Bt,
    const float* __restrict__ bias, void* __restrict__ Cout,
    int M, int N, int K, int NTN) {
    __shared__ u16 lA[128 * 64];
    __shared__ u16 lB[128 * 64];
    int nwg = gridDim.x;
    int bid = blockIdx.x;
    int wg = ((nwg & 7) == 0) ? ((bid & 7) * (nwg >> 3) + (bid >> 3)) : bid;
    int mt = wg / NTN, nt = wg % NTN;
    int row0 = mt << 7, col0 = nt << 7;
    int tid = threadIdx.x;
    int lane = tid & 63, wv = tid >> 6;
    int wm = (wv >> 1) * 64, wn = (wv & 1) * 64;
    int l15 = lane & 15, hi = lane >> 4;

    f32x4 acc[4][4] = {};

    for (int kt = 0; kt < K; kt += 64) {
        __syncthreads();
        #pragma unroll
        for (int p = 0; p < 4; ++p) {
            int cl = p * 256 + tid;
            int rr = cl >> 3;
            int cc = (cl & 7) ^ (rr & 7);
            int lo = (p * 256 + (wv << 6)) << 3;
            load_lds16(A + (size_t)(row0 + rr) * K + kt + cc * 8, &lA[lo]);
            load_lds16(Bt + (size_t)(col0 + rr) * K + kt + cc * 8, &lB[lo]);
        }
        __syncthreads();
        __builtin_amdgcn_s_setprio(1);
        #pragma unroll
        for (int ks = 0; ks < 2; ++ks) {
            bf16x8 af[4], bf[4];
            #pragma unroll
            for (int i = 0; i < 4; ++i) {
                int ra = wm + i * 16 + l15;
                af[i] = *(const bf16x8*)&lA[ra * 64 + (((ks << 2) + hi) ^ (ra & 7)) * 8];
                int rb = wn + i * 16 + l15;
                bf[i] = *(const bf16x8*)&lB[rb * 64 + (((ks << 2) + hi) ^ (rb & 7)) * 8];
            }
            #pragma unroll
            for (int mi = 0; mi < 4; ++mi)
                #pragma unroll
                for (int ni = 0; ni < 4; ++ni)
                    acc[mi][ni] = __builtin_amdgcn_mfma_f32_16x16x32_bf16(
                        af[mi], bf[ni], acc[mi][ni], 0, 0, 0);
        }
        __builtin_amdgcn_s_setprio(0);
    }

    #pragma unroll
    for (int mi = 0; mi < 4; ++mi) {
        int rbase = row0 + wm + mi * 16 + hi * 4;
        #pragma unroll
        for (int ni = 0; ni < 4; ++ni) {
            int c = col0 + wn + ni * 16 + l15;
            float bv = bias[c];
            #pragma unroll
            for (int j = 0; j < 4; ++j) {
                float o = acc[mi][ni][j] + bv;
                if (F32OUT) ((float*)Cout)[(size_t)(rbase + j) * N + c] = o;
                else        ((u16*)Cout)[(size_t)(rbase + j) * N + c] = f2b(o);
            }
        }
    }
}

// ---------------- flash attention (swapped QK^T, zero-shuffle PV, kvb-seq) --
// 32x32x16 MFMAs, S^T = mfma(K,Q). No-max softmax (exp2-domain, bounded).
// kvb processed SEQUENTIALLY (QK -> exp2/cvt -> PV per 32-kv half) so accs(16)
// and W(8) are dead before the next half: peak regs ~130 -> 3 waves/SIMD.
// PV needs no cross-lane exchange: V^T stored at b2<->b3-swapped columns makes
// the contiguous V-read match the accs register k-slot order exactly.
__global__ __launch_bounds__(256, 3) void attn_kernel(
    const u16* __restrict__ QKV, u16* __restrict__ ctx) {
    __shared__ u16 lK[2][64 * 64];    // K-tile [kv][d], XOR-swizzled 16B chunks
    __shared__ u16 lV[2][64 * 68];    // V^T tile [d][kv'], kv' = b2<->b3 swap, +4 pad

    int bid = blockIdx.x;
    int wg = (bid & 7) * 192 + (bid >> 3);   // XCD swizzle
    int bh = wg >> 3, qt = wg & 7;
    int b = bh / 12, h = bh % 12;
    int tid = threadIdx.x;
    int lane = tid & 63, wv = tid >> 6;
    int l31 = lane & 31;
    int hb = lane >> 5;

    const u16* Qb = QKV + (size_t)b * 1024 * 2304 + h * 64;
    const u16* Kb = Qb + 768;
    const u16* Vb = Qb + 1536;

    int qrow0 = qt * 128 + wv * 32;

    // Q as B-operand: lane -> col q = l31, k(d) slots
    bf16x8 qf[4];
    #pragma unroll
    for (int ks = 0; ks < 4; ++ks)
        qf[ks] = *(const bf16x8*)(Qb + (size_t)(qrow0 + l31) * 2304 + ks * 16 + hb * 8);

    bf16x8 ones;
    #pragma unroll
    for (int i = 0; i < 8; ++i) ones[i] = (short)0x3F80;  // bf16 1.0

    f32x16 accO0 = {}, accO1 = {};   // d-blocks 0/1
    f32x16 accL = {};                // row sums, same C-layout rows as accO

    // staging geometry
    int jj0 = (tid & 31) * 2;                   // V: 2 adjacent kv rows / thread
    int jjs = (jj0 & ~12) | ((jj0 & 4) << 1) | ((jj0 & 8) >> 1);  // b2<->b3 swap
    int d0v = (tid >> 5) << 3;                  // V: 8-wide d block

    // ---- prologue: stage tile 0 into buffer 0 ----
    #pragma unroll
    for (int p = 0; p < 2; ++p) {
        int rr = (p * 256 + tid) >> 3;
        int cc = ((p * 256 + tid) & 7) ^ (rr & 7);
        load_lds16(Kb + (size_t)rr * 2304 + cc * 8, &lK[0][(p * 256 + (wv << 6)) << 3]);
    }
    {
        bf16x8 g0 = *(const bf16x8*)(Vb + (size_t)jj0 * 2304 + d0v);
        bf16x8 g1 = *(const bf16x8*)(Vb + (size_t)(jj0 + 1) * 2304 + d0v);
        const unsigned* a0 = (const unsigned*)&g0;
        const unsigned* a1 = (const unsigned*)&g1;
        #pragma unroll
        for (int w = 0; w < 4; ++w) {
            *(unsigned*)&lV[0][(d0v + 2 * w) * 68 + jjs] =
                __builtin_amdgcn_perm(a1[w], a0[w], 0x05040100);
            *(unsigned*)&lV[0][(d0v + 2 * w + 1) * 68 + jjs] =
                __builtin_amdgcn_perm(a1[w], a0[w], 0x07060302);
        }
    }
    __syncthreads();

    int cur = 0;
    for (int t = 0; t < 16; ++t) {
        // ---- issue prefetch for tile t+1 into buffer cur^1 (early) ----
        bf16x8 nv0, nv1;
        if (t < 15) {
            size_t kt1 = (size_t)(t + 1) * 64;
            #pragma unroll
            for (int p = 0; p < 2; ++p) {
                int rr = (p * 256 + tid) >> 3;
                int cc = ((p * 256 + tid) & 7) ^ (rr & 7);
                load_lds16(Kb + (kt1 + rr) * 2304 + cc * 8,
                           &lK[cur ^ 1][(p * 256 + (wv << 6)) << 3]);
            }
            nv0 = *(const bf16x8*)(Vb + (kt1 + jj0) * 2304 + d0v);
            nv1 = *(const bf16x8*)(Vb + (kt1 + jj0 + 1) * 2304 + d0v);
        }

        // ---- per 32-kv half: QK -> softmax -> PV (accs/W die each half) ----
        #pragma unroll
        for (int kvb = 0; kvb < 2; ++kvb) {
            f32x16 accs = {};
            __builtin_amdgcn_s_setprio(1);
            #pragma unroll
            for (int ks = 0; ks < 4; ++ks) {
                bf16x8 kf = *(const bf16x8*)&lK[cur][
                    (kvb * 32 + l31) * 64 + (((ks << 1) + hb) ^ (l31 & 7)) * 8];
                accs = __builtin_amdgcn_mfma_f32_32x32x16_bf16(kf, qf[ks], accs, 0, 0, 0);
            }
            __builtin_amdgcn_s_setprio(0);

            unsigned W[8];
            #pragma unroll
            for (int w = 0; w < 8; ++w)
                W[w] = cvt_pk_bf16(exp2f(accs[2 * w]), exp2f(accs[2 * w + 1]));

            __builtin_amdgcn_s_setprio(1);
            #pragma unroll
            for (int mm = 0; mm < 2; ++mm) {
                int m = kvb * 2 + mm;
                u32x4 pw;
                pw.x = W[4 * mm];     pw.y = W[4 * mm + 1];
                pw.z = W[4 * mm + 2]; pw.w = W[4 * mm + 3];
                bf16x8 pa = *(bf16x8*)&pw;
                accL = __builtin_amdgcn_mfma_f32_32x32x16_bf16(pa, ones, accL, 0, 0, 0);
                bf16x8 vf0 = *(const bf16x8*)&lV[cur][l31 * 68 + m * 16 + hb * 8];
                bf16x8 vf1 = *(const bf16x8*)&lV[cur][(32 + l31) * 68 + m * 16 + hb * 8];
                accO0 = __builtin_amdgcn_mfma_f32_32x32x16_bf16(pa, vf0, accO0, 0, 0, 0);
                accO1 = __builtin_amdgcn_mfma_f32_32x32x16_bf16(pa, vf1, accO1, 0, 0, 0);
            }
            __builtin_amdgcn_s_setprio(0);
        }

        // ---- write-late: V(t+1) pack into lV[cur^1] at permuted columns ----
        if (t < 15) {
            const unsigned* a0 = (const unsigned*)&nv0;
            const unsigned* a1 = (const unsigned*)&nv1;
            #pragma unroll
            for (int w = 0; w < 4; ++w) {
                *(unsigned*)&lV[cur ^ 1][(d0v + 2 * w) * 68 + jjs] =
                    __builtin_amdgcn_perm(a1[w], a0[w], 0x05040100);
                *(unsigned*)&lV[cur ^ 1][(d0v + 2 * w + 1) * 68 + jjs] =
                    __builtin_amdgcn_perm(a1[w], a0[w], 0x07060302);
            }
        }

        __syncthreads();
        cur ^= 1;
    }

    // ---- epilogue: O /= L (row layouts match), write ctx bf16 [B*S][768] ----
    #pragma unroll
    for (int r = 0; r < 16; ++r) {
        float inv = 1.0f / accL[r];
        int q = (r & 3) + 8 * (r >> 2) + hb * 4;
        size_t row = (size_t)(b * 1024 + qrow0 + q);
        ctx[row * 768 + h * 64 + l31]      = f2b(accO0[r] * inv);
        ctx[row * 768 + h * 64 + 32 + l31] = f2b(accO1[r] * inv);
    }
}

// ---------------- launcher ----------------
extern "C" void kernel_launch(void* const* d_in, const int* in_sizes, int n_in,
                              void* d_out, int out_size, void* d_ws, size_t ws_size,
                              hipStream_t stream) {
    const float* x  = (const float*)d_in[0];
    const float* ci = (const float*)d_in[1];
    const float* cc = (const float*)d_in[2];
    const float* Wq = (const float*)d_in[3];
    const float* bq = (const float*)d_in[4];
    const float* Wk = (const float*)d_in[5];
    const float* bk = (const float*)d_in[6];
    const float* Wv = (const float*)d_in[7];
    const float* bv = (const float*)d_in[8];
    const float* Wo = (const float*)d_in[9];
    const float* bo = (const float*)d_in[10];
    float* out = (float*)d_out;

    unsigned char* ws = (unsigned char*)d_ws;
    size_t off = 0;
    auto alloc = [&](size_t bytes) {
        void* p = ws + off;
        off += (bytes + 255) & ~(size_t)255;
        return p;
    };
    u16*   hbuf  = (u16*)  alloc((size_t)16384 * 768 * 2);
    u16*   wqkvt = (u16*)  alloc((size_t)2304 * 768 * 2);
    u16*   wot   = (u16*)  alloc((size_t)768 * 768 * 2);
    float* biasq = (float*)alloc(2304 * 4);
    u16*   qkv   = (u16*)  alloc((size_t)16384 * 2304 * 2);
    u16*   ctx   = (u16*)  alloc((size_t)16384 * 768 * 2);

    prep_hidden<<<12288, 256, 0, stream>>>(x, ci, hbuf);
    transpose_w<<<dim3(24, 24, 4), 256, 0, stream>>>(Wq, Wk, Wv, Wo, cc, wqkvt, wot);
    bias_cat<<<9, 256, 0, stream>>>(bq, bk, bv, biasq);
    gemm_bt<0><<<2304, 256, 0, stream>>>(hbuf, wqkvt, biasq, qkv, 16384, 2304, 768, 18);
    attn_kernel<<<1536, 256, 0, stream>>>(qkv, ctx);
    gemm_bt<1><<<768, 256, 0, stream>>>(ctx, wot, bo, out, 16384, 768, 768, 6);
}

// Round 11
// 185.511 us; speedup vs baseline: 1.4479x; 1.0909x over previous
//
#include <hip/hip_runtime.h>
#include <hip/hip_bf16.h>

typedef unsigned short u16;
typedef short bf16x8 __attribute__((ext_vector_type(8)));
typedef float f32x4 __attribute__((ext_vector_type(4)));
typedef float f32x16 __attribute__((ext_vector_type(16)));
typedef unsigned short u16x4 __attribute__((ext_vector_type(4)));
typedef unsigned u32x4 __attribute__((ext_vector_type(4)));

// scores pre-scaled by log2(e)/8 (folded into Wq, bq) so softmax is pure exp2
#define SCALE_Q 0.18033688011112042f

__device__ __forceinline__ u16 f2b(float f) {
    __hip_bfloat16 h = __float2bfloat16(f);   // hw v_cvt (RNE) on gfx950
    return *reinterpret_cast<u16*>(&h);
}

__device__ __forceinline__ unsigned cvt_pk_bf16(float lo, float hi) {
    unsigned r;
    asm("v_cvt_pk_bf16_f32 %0, %1, %2" : "=v"(r) : "v"(lo), "v"(hi));
    return r;
}

// single-instruction exp2/rcp via BUILTINS (not inline asm): the compiler
// emits v_exp_f32/v_rcp_f32 itself and inserts the required TRANS-use
// wait-states. R10's inline-asm version defeated hazard insertion -> wrong
// values (absmax 1e-2). Accuracy ~1 ulp, invisible at bf16.
#define hw_exp2 __builtin_amdgcn_exp2f
#define hw_rcp  __builtin_amdgcn_rcpf

__device__ __forceinline__ void load_lds16(const void* g, void* l) {
    __builtin_amdgcn_global_load_lds(
        (const __attribute__((address_space(1))) void*)g,
        (__attribute__((address_space(3))) void*)l, 16, 0, 0);
}

// ---------------- prep: hidden * channel_importance -> bf16 ----------------
__global__ __launch_bounds__(256) void prep_hidden(
    const float* __restrict__ x, const float* __restrict__ ci, u16* __restrict__ hbuf) {
    size_t i = ((size_t)blockIdx.x * 256 + threadIdx.x) * 4;
    float4 v = *(const float4*)(x + i);
    int c = (int)(i % 768);
    u16x4 o;
    o.x = f2b(v.x * ci[c]);     o.y = f2b(v.y * ci[c + 1]);
    o.z = f2b(v.z * ci[c + 2]); o.w = f2b(v.w * ci[c + 3]);
    *(u16x4*)(hbuf + i) = o;
}

// ---------------- prep: transpose weights to [N][K] bf16 ----------------
__global__ __launch_bounds__(256) void transpose_w(
    const float* __restrict__ Wq, const float* __restrict__ Wk,
    const float* __restrict__ Wv, const float* __restrict__ Wo,
    const float* __restrict__ cc, u16* __restrict__ wqkvt, u16* __restrict__ wot) {
    __shared__ float tile[32][33];
    int z = blockIdx.z;
    const float* src = (z == 0) ? Wq : (z == 1) ? Wk : (z == 2) ? Wv : Wo;
    u16* dst = (z < 3) ? (wqkvt + (size_t)z * 768 * 768) : wot;
    int tx = threadIdx.x & 31, ty = threadIdx.x >> 5;
    int k0 = blockIdx.x * 32, n0 = blockIdx.y * 32;
    #pragma unroll
    for (int i = ty; i < 32; i += 8) {
        float v = src[(size_t)(k0 + i) * 768 + n0 + tx];
        if (z == 3) v *= cc[k0 + i];
        if (z == 0) v *= SCALE_Q;
        tile[i][tx] = v;
    }
    __syncthreads();
    #pragma unroll
    for (int i = ty; i < 32; i += 8)
        dst[(size_t)(n0 + i) * 768 + k0 + tx] = f2b(tile[tx][i]);
}

__global__ __launch_bounds__(256) void bias_cat(
    const float* __restrict__ bq, const float* __restrict__ bk,
    const float* __restrict__ bv, float* __restrict__ biasq) {
    int i = blockIdx.x * 256 + threadIdx.x;
    biasq[i] = (i < 768) ? bq[i] * SCALE_Q : (i < 1536) ? bk[i - 768] : bv[i - 1536];
}

// ---------------- GEMM: C[M][N] = A[M][K] @ Bt[N][K]^T + bias ----------------
template <int F32OUT>
__global__ __launch_bounds__(256) void gemm_bt(
    const u16* __restrict__ A, const u16* __restrict__ Bt,
    const float* __restrict__ bias, void* __restrict__ Cout,
    int M, int N, int K, int NTN) {
    __shared__ u16 lA[128 * 64];
    __shared__ u16 lB[128 * 64];
    int nwg = gridDim.x;
    int bid = blockIdx.x;
    int wg = ((nwg & 7) == 0) ? ((bid & 7) * (nwg >> 3) + (bid >> 3)) : bid;
    int mt = wg / NTN, nt = wg % NTN;
    int row0 = mt << 7, col0 = nt << 7;
    int tid = threadIdx.x;
    int lane = tid & 63, wv = tid >> 6;
    int wm = (wv >> 1) * 64, wn = (wv & 1) * 64;
    int l15 = lane & 15, hi = lane >> 4;

    f32x4 acc[4][4] = {};

    for (int kt = 0; kt < K; kt += 64) {
        __syncthreads();
        #pragma unroll
        for (int p = 0; p < 4; ++p) {
            int cl = p * 256 + tid;
            int rr = cl >> 3;
            int cc = (cl & 7) ^ (rr & 7);
            int lo = (p * 256 + (wv << 6)) << 3;
            load_lds16(A + (size_t)(row0 + rr) * K + kt + cc * 8, &lA[lo]);
            load_lds16(Bt + (size_t)(col0 + rr) * K + kt + cc * 8, &lB[lo]);
        }
        __syncthreads();
        __builtin_amdgcn_s_setprio(1);
        #pragma unroll
        for (int ks = 0; ks < 2; ++ks) {
            bf16x8 af[4], bf[4];
            #pragma unroll
            for (int i = 0; i < 4; ++i) {
                int ra = wm + i * 16 + l15;
                af[i] = *(const bf16x8*)&lA[ra * 64 + (((ks << 2) + hi) ^ (ra & 7)) * 8];
                int rb = wn + i * 16 + l15;
                bf[i] = *(const bf16x8*)&lB[rb * 64 + (((ks << 2) + hi) ^ (rb & 7)) * 8];
            }
            #pragma unroll
            for (int mi = 0; mi < 4; ++mi)
                #pragma unroll
                for (int ni = 0; ni < 4; ++ni)
                    acc[mi][ni] = __builtin_amdgcn_mfma_f32_16x16x32_bf16(
                        af[mi], bf[ni], acc[mi][ni], 0, 0, 0);
        }
        __builtin_amdgcn_s_setprio(0);
    }

    #pragma unroll
    for (int mi = 0; mi < 4; ++mi) {
        int rbase = row0 + wm + mi * 16 + hi * 4;
        #pragma unroll
        for (int ni = 0; ni < 4; ++ni) {
            int c = col0 + wn + ni * 16 + l15;
            float bv = bias[c];
            #pragma unroll
            for (int j = 0; j < 4; ++j) {
                float o = acc[mi][ni][j] + bv;
                if (F32OUT) ((float*)Cout)[(size_t)(rbase + j) * N + c] = o;
                else        ((u16*)Cout)[(size_t)(rbase + j) * N + c] = f2b(o);
            }
        }
    }
}

// ---------------- flash attention (swapped QK^T, zero-shuffle PV, kvb-seq) --
// 32x32x16 MFMAs, S^T = mfma(K,Q). No-max softmax (exp2-domain, bounded);
// exp2 via __builtin_amdgcn_exp2f (1 instr, hazard-safe). kvb processed
// sequentially so accs(16)/W(8) die each half: 64 VGPR, 3 waves/SIMD.
// PV needs no cross-lane exchange: V^T stored at b2<->b3-swapped columns
// matches the accs register k-slot order exactly.
__global__ __launch_bounds__(256, 3) void attn_kernel(
    const u16* __restrict__ QKV, u16* __restrict__ ctx) {
    __shared__ u16 lK[2][64 * 64];    // K-tile [kv][d], XOR-swizzled 16B chunks
    __shared__ u16 lV[2][64 * 68];    // V^T tile [d][kv'], kv' = b2<->b3 swap, +4 pad

    int bid = blockIdx.x;
    int wg = (bid & 7) * 192 + (bid >> 3);   // XCD swizzle
    int bh = wg >> 3, qt = wg & 7;
    int b = bh / 12, h = bh % 12;
    int tid = threadIdx.x;
    int lane = tid & 63, wv = tid >> 6;
    int l31 = lane & 31;
    int hb = lane >> 5;

    const u16* Qb = QKV + (size_t)b * 1024 * 2304 + h * 64;
    const u16* Kb = Qb + 768;
    const u16* Vb = Qb + 1536;

    int qrow0 = qt * 128 + wv * 32;

    // Q as B-operand: lane -> col q = l31, k(d) slots
    bf16x8 qf[4];
    #pragma unroll
    for (int ks = 0; ks < 4; ++ks)
        qf[ks] = *(const bf16x8*)(Qb + (size_t)(qrow0 + l31) * 2304 + ks * 16 + hb * 8);

    bf16x8 ones;
    #pragma unroll
    for (int i = 0; i < 8; ++i) ones[i] = (short)0x3F80;  // bf16 1.0

    f32x16 accO0 = {}, accO1 = {};   // d-blocks 0/1
    f32x16 accL = {};                // row sums, same C-layout rows as accO

    // staging geometry
    int jj0 = (tid & 31) * 2;                   // V: 2 adjacent kv rows / thread
    int jjs = (jj0 & ~12) | ((jj0 & 4) << 1) | ((jj0 & 8) >> 1);  // b2<->b3 swap
    int d0v = (tid >> 5) << 3;                  // V: 8-wide d block

    // ---- prologue: stage tile 0 into buffer 0 ----
    #pragma unroll
    for (int p = 0; p < 2; ++p) {
        int rr = (p * 256 + tid) >> 3;
        int cc = ((p * 256 + tid) & 7) ^ (rr & 7);
        load_lds16(Kb + (size_t)rr * 2304 + cc * 8, &lK[0][(p * 256 + (wv << 6)) << 3]);
    }
    {
        bf16x8 g0 = *(const bf16x8*)(Vb + (size_t)jj0 * 2304 + d0v);
        bf16x8 g1 = *(const bf16x8*)(Vb + (size_t)(jj0 + 1) * 2304 + d0v);
        const unsigned* a0 = (const unsigned*)&g0;
        const unsigned* a1 = (const unsigned*)&g1;
        #pragma unroll
        for (int w = 0; w < 4; ++w) {
            *(unsigned*)&lV[0][(d0v + 2 * w) * 68 + jjs] =
                __builtin_amdgcn_perm(a1[w], a0[w], 0x05040100);
            *(unsigned*)&lV[0][(d0v + 2 * w + 1) * 68 + jjs] =
                __builtin_amdgcn_perm(a1[w], a0[w], 0x07060302);
        }
    }
    __syncthreads();

    int cur = 0;
    for (int t = 0; t < 16; ++t) {
        // ---- issue prefetch for tile t+1 into buffer cur^1 (early) ----
        bf16x8 nv0, nv1;
        if (t < 15) {
            size_t kt1 = (size_t)(t + 1) * 64;
            #pragma unroll
            for (int p = 0; p < 2; ++p) {
                int rr = (p * 256 + tid) >> 3;
                int cc = ((p * 256 + tid) & 7) ^ (rr & 7);
                load_lds16(Kb + (kt1 + rr) * 2304 + cc * 8,
                           &lK[cur ^ 1][(p * 256 + (wv << 6)) << 3]);
            }
            nv0 = *(const bf16x8*)(Vb + (kt1 + jj0) * 2304 + d0v);
            nv1 = *(const bf16x8*)(Vb + (kt1 + jj0 + 1) * 2304 + d0v);
        }

        // ---- per 32-kv half: QK -> softmax -> PV (accs/W die each half) ----
        #pragma unroll
        for (int kvb = 0; kvb < 2; ++kvb) {
            f32x16 accs = {};
            __builtin_amdgcn_s_setprio(1);
            #pragma unroll
            for (int ks = 0; ks < 4; ++ks) {
                bf16x8 kf = *(const bf16x8*)&lK[cur][
                    (kvb * 32 + l31) * 64 + (((ks << 1) + hb) ^ (l31 & 7)) * 8];
                accs = __builtin_amdgcn_mfma_f32_32x32x16_bf16(kf, qf[ks], accs, 0, 0, 0);
            }
            __builtin_amdgcn_s_setprio(0);

            unsigned W[8];
            #pragma unroll
            for (int w = 0; w < 8; ++w)
                W[w] = cvt_pk_bf16(hw_exp2(accs[2 * w]), hw_exp2(accs[2 * w + 1]));

            __builtin_amdgcn_s_setprio(1);
            #pragma unroll
            for (int mm = 0; mm < 2; ++mm) {
                int m = kvb * 2 + mm;
                u32x4 pw;
                pw.x = W[4 * mm];     pw.y = W[4 * mm + 1];
                pw.z = W[4 * mm + 2]; pw.w = W[4 * mm + 3];
                bf16x8 pa = *(bf16x8*)&pw;
                accL = __builtin_amdgcn_mfma_f32_32x32x16_bf16(pa, ones, accL, 0, 0, 0);
                bf16x8 vf0 = *(const bf16x8*)&lV[cur][l31 * 68 + m * 16 + hb * 8];
                bf16x8 vf1 = *(const bf16x8*)&lV[cur][(32 + l31) * 68 + m * 16 + hb * 8];
                accO0 = __builtin_amdgcn_mfma_f32_32x32x16_bf16(pa, vf0, accO0, 0, 0, 0);
                accO1 = __builtin_amdgcn_mfma_f32_32x32x16_bf16(pa, vf1, accO1, 0, 0, 0);
            }
            __builtin_amdgcn_s_setprio(0);
        }

        // ---- write-late: V(t+1) pack into lV[cur^1] at permuted columns ----
        if (t < 15) {
            const unsigned* a0 = (const unsigned*)&nv0;
            const unsigned* a1 = (const unsigned*)&nv1;
            #pragma unroll
            for (int w = 0; w < 4; ++w) {
                *(unsigned*)&lV[cur ^ 1][(d0v + 2 * w) * 68 + jjs] =
                    __builtin_amdgcn_perm(a1[w], a0[w], 0x05040100);
                *(unsigned*)&lV[cur ^ 1][(d0v + 2 * w + 1) * 68 + jjs] =
                    __builtin_amdgcn_perm(a1[w], a0[w], 0x07060302);
            }
        }

        __syncthreads();
        cur ^= 1;
    }

    // ---- epilogue: O /= L (row layouts match), write ctx bf16 [B*S][768] ----
    #pragma unroll
    for (int r = 0; r < 16; ++r) {
        float inv = hw_rcp(accL[r]);
        int q = (r & 3) + 8 * (r >> 2) + hb * 4;
        size_t row = (size_t)(b * 1024 + qrow0 + q);
        ctx[row * 768 + h * 64 + l31]      = f2b(accO0[r] * inv);
        ctx[row * 768 + h * 64 + 32 + l31] = f2b(accO1[r] * inv);
    }
}

// ---------------- launcher ----------------
extern "C" void kernel_launch(void* const* d_in, const int* in_sizes, int n_in,
                              void* d_out, int out_size, void* d_ws, size_t ws_size,
                              hipStream_t stream) {
    const float* x  = (const float*)d_in[0];
    const float* ci = (const float*)d_in[1];
    const float* cc = (const float*)d_in[2];
    const float* Wq = (const float*)d_in[3];
    const float* bq = (const float*)d_in[4];
    const float* Wk = (const float*)d_in[5];
    const float* bk = (const float*)d_in[6];
    const float* Wv = (const float*)d_in[7];
    const float* bv = (const float*)d_in[8];
    const float* Wo = (const float*)d_in[9];
    const float* bo = (const float*)d_in[10];
    float* out = (float*)d_out;

    unsigned char* ws = (unsigned char*)d_ws;
    size_t off = 0;
    auto alloc = [&](size_t bytes) {
        void* p = ws + off;
        off += (bytes + 255) & ~(size_t)255;
        return p;
    };
    u16*   hbuf  = (u16*)  alloc((size_t)16384 * 768 * 2);
    u16*   wqkvt = (u16*)  alloc((size_t)2304 * 768 * 2);
    u16*   wot   = (u16*)  alloc((size_t)768 * 768 * 2);
    float* biasq = (float*)alloc(2304 * 4);
    u16*   qkv   = (u16*)  alloc((size_t)16384 * 2304 * 2);
    u16*   ctx   = (u16*)  alloc((size_t)16384 * 768 * 2);

    prep_hidden<<<12288, 256, 0, stream>>>(x, ci, hbuf);
    transpose_w<<<dim3(24, 24, 4), 256, 0, stream>>>(Wq, Wk, Wv, Wo, cc, wqkvt, wot);
    bias_cat<<<9, 256, 0, stream>>>(bq, bk, bv, biasq);
    gemm_bt<0><<<2304, 256, 0, stream>>>(hbuf, wqkvt, biasq, qkv, 16384, 2304, 768, 18);
    attn_kernel<<<1536, 256, 0, stream>>>(qkv, ctx);
    gemm_bt<1><<<768, 256, 0, stream>>>(ctx, wot, bo, out, 16384, 768, 768, 6);
}